// Round 2
// baseline (677.059 us; speedup 1.0000x reference)
//
#include <hip/hip_runtime.h>
#include <math.h>

#define NEG_SLOPE 0.2f

__device__ __forceinline__ unsigned int enc_f(float f) {
    unsigned int b = __float_as_uint(f);
    return (b & 0x80000000u) ? ~b : (b | 0x80000000u);
}
__device__ __forceinline__ float dec_f(unsigned int u) {
    unsigned int b = (u & 0x80000000u) ? (u & 0x7FFFFFFFu) : ~u;
    return __uint_as_float(b);
}
__device__ __forceinline__ float leaky(float v) { return v >= 0.0f ? v : NEG_SLOPE * v; }

// K1: h = x @ W  (IN=128, OUT=64), fused a_s = h@att_src, a_d = h@att_dst,
// and seg_max init with the self-loop logit.
// Block = 256 threads (4 waves), 32 nodes per block. W staged in LDS (32 KB),
// 32 x-rows staged in LDS (16 KB).
__global__ __launch_bounds__(256) void k_linear(
    const float* __restrict__ x, const float* __restrict__ W,
    const float* __restrict__ att_src, const float* __restrict__ att_dst,
    float* __restrict__ h, float* __restrict__ a_s, float* __restrict__ a_d,
    unsigned int* __restrict__ seg_max_enc, int N)
{
    __shared__ float sW[128 * 64];
    __shared__ float sx[32 * 128];
    const int tid  = threadIdx.x;
    const int base = blockIdx.x * 32;

    // stage W: 8192 floats = 2048 float4
    const float4* W4  = (const float4*)W;
    float4*       sW4 = (float4*)sW;
#pragma unroll
    for (int i = 0; i < 8; ++i) sW4[tid + i * 256] = W4[tid + i * 256];

    // stage x rows (contiguous block of 32 rows): 4096 floats = 1024 float4
    const int nvalid = (N - base) < 32 ? (N - base) : 32;
    const int lim4   = nvalid * 32;
    const float4* x4  = (const float4*)x + (size_t)base * 32;
    float4*       sx4 = (float4*)sx;
#pragma unroll
    for (int i = 0; i < 4; ++i) {
        int idx = tid + i * 256;
        if (idx < lim4) sx4[idx] = x4[idx];
    }
    __syncthreads();

    const int o = tid & 63;   // output feature
    const int w = tid >> 6;   // wave id: handles nodes base + w*8 .. +7

    float acc[8];
#pragma unroll
    for (int j = 0; j < 8; ++j) acc[j] = 0.0f;

    const float* sxw = sx + (w * 8) * 128;
    for (int k = 0; k < 128; ++k) {
        float wk = sW[k * 64 + o];         // lanes consecutive -> conflict-free
#pragma unroll
        for (int j = 0; j < 8; ++j) acc[j] += sxw[j * 128 + k] * wk;  // LDS broadcast
    }

    const float vs = att_src[o];
    const float vd = att_dst[o];
#pragma unroll
    for (int j = 0; j < 8; ++j) {
        int n = base + w * 8 + j;
        if (n < N) {
            h[(size_t)n * 64 + o] = acc[j];
            float s = acc[j] * vs;
            float d = acc[j] * vd;
#pragma unroll
            for (int m = 32; m > 0; m >>= 1) {
                s += __shfl_xor(s, m, 64);
                d += __shfl_xor(d, m, 64);
            }
            if (o == 0) {
                a_s[n] = s;
                a_d[n] = d;
                seg_max_enc[n] = enc_f(leaky(s + d));  // self-loop logit
            }
        }
    }
}

// K2: per-edge segment max (ordered-uint atomicMax). edge_index is int32!
__global__ __launch_bounds__(256) void k_edge_max(
    const int* __restrict__ ei, const float* __restrict__ a_s,
    const float* __restrict__ a_d, unsigned int* __restrict__ seg_max_enc,
    int E)
{
    int t = blockIdx.x * 256 + threadIdx.x;
    if (t >= E) return;
    int src = ei[t];
    int dst = ei[E + t];
    float e = leaky(a_s[src] + a_d[dst]);
    atomicMax(seg_max_enc + dst, enc_f(e));
}

// K3: decode seg_max, init seg_sum with the self-loop exp term.
__global__ __launch_bounds__(256) void k_node_fin(
    const float* __restrict__ a_s, const float* __restrict__ a_d,
    const unsigned int* __restrict__ seg_max_enc,
    float* __restrict__ seg_max_f, float* __restrict__ seg_sum, int N)
{
    int n = blockIdx.x * 256 + threadIdx.x;
    if (n >= N) return;
    float mx = dec_f(seg_max_enc[n]);
    seg_max_f[n] = mx;
    float es = leaky(a_s[n] + a_d[n]);
    seg_sum[n] = expf(es - mx);
}

// K4: per-edge exp-sum into seg_sum[dst].
__global__ __launch_bounds__(256) void k_edge_sum(
    const int* __restrict__ ei, const float* __restrict__ a_s,
    const float* __restrict__ a_d, const float* __restrict__ seg_max_f,
    float* __restrict__ seg_sum, int E)
{
    int t = blockIdx.x * 256 + threadIdx.x;
    if (t >= E) return;
    int src = ei[t];
    int dst = ei[E + t];
    float e = leaky(a_s[src] + a_d[dst]);
    atomicAdd(seg_sum + dst, expf(e - seg_max_f[dst]));
}

// K5: out = bias + alpha_self * h  (non-atomic init of d_out).
__global__ __launch_bounds__(256) void k_node_out(
    const float* __restrict__ h, const float* __restrict__ a_s,
    const float* __restrict__ a_d, const float* __restrict__ seg_max_f,
    const float* __restrict__ seg_sum, const float* __restrict__ bias,
    float* __restrict__ out, int N)
{
    size_t i = (size_t)blockIdx.x * 256 + threadIdx.x;
    int n = (int)(i >> 6);
    int o = (int)(i & 63);
    if (n >= N) return;
    float alpha = expf(leaky(a_s[n] + a_d[n]) - seg_max_f[n]) / seg_sum[n];
    out[i] = bias[o] + alpha * h[i];
}

// K6: one wave per edge, lane = feature. Coalesced gather of h[src],
// scalar fp32 atomicAdd scatter into out[dst].
__global__ __launch_bounds__(256) void k_edge_agg(
    const int* __restrict__ ei, const float* __restrict__ a_s,
    const float* __restrict__ a_d, const float* __restrict__ seg_max_f,
    const float* __restrict__ seg_sum, const float* __restrict__ h,
    float* __restrict__ out, int E)
{
    long long wid = ((long long)blockIdx.x * 256 + threadIdx.x) >> 6;
    int lane = threadIdx.x & 63;
    if (wid >= E) return;
    int src = ei[wid];
    int dst = ei[E + wid];
    float alpha = expf(leaky(a_s[src] + a_d[dst]) - seg_max_f[dst]) / seg_sum[dst];
    float v = h[(size_t)src * 64 + lane];
    atomicAdd(out + (size_t)dst * 64 + lane, alpha * v);
}

extern "C" void kernel_launch(void* const* d_in, const int* in_sizes, int n_in,
                              void* d_out, int out_size, void* d_ws, size_t ws_size,
                              hipStream_t stream)
{
    const float* x       = (const float*)d_in[0];
    const int*   ei      = (const int*)d_in[1];      // int32 per harness contract
    const float* W       = (const float*)d_in[2];
    const float* att_src = (const float*)d_in[3];
    const float* att_dst = (const float*)d_in[4];
    const float* bias    = (const float*)d_in[5];
    float*       out     = (float*)d_out;

    const int N = in_sizes[0] / 128;   // 100000
    const int E = in_sizes[1] / 2;     // 1600000

    // workspace layout (fp32 slots): h[N*64] | a_s[N] | a_d[N] | enc[N] | mx[N] | sum[N]
    float*        h    = (float*)d_ws;
    float*        a_s  = h + (size_t)N * 64;
    float*        a_d  = a_s + N;
    unsigned int* enc  = (unsigned int*)(a_d + N);
    float*        mx   = (float*)(enc + N);
    float*        ssum = mx + N;

    int nb_lin  = (N + 31) / 32;
    int nb_node = (N + 255) / 256;
    int nb_edge = (E + 255) / 256;
    int nb_out  = (int)(((size_t)N * 64 + 255) / 256);
    int nb_agg  = (int)(((long long)E * 64 + 255) / 256);

    k_linear  <<<nb_lin,  256, 0, stream>>>(x, W, att_src, att_dst, h, a_s, a_d, enc, N);
    k_edge_max<<<nb_edge, 256, 0, stream>>>(ei, a_s, a_d, enc, E);
    k_node_fin<<<nb_node, 256, 0, stream>>>(a_s, a_d, enc, mx, ssum, N);
    k_edge_sum<<<nb_edge, 256, 0, stream>>>(ei, a_s, a_d, mx, ssum, E);
    k_node_out<<<nb_out,  256, 0, stream>>>(h, a_s, a_d, mx, ssum, bias, out, N);
    k_edge_agg<<<nb_agg,  256, 0, stream>>>(ei, a_s, a_d, mx, ssum, h, out, E);
}

// Round 5
// 459.552 us; speedup vs baseline: 1.4733x; 1.4733x over previous
//
#include <hip/hip_runtime.h>
#include <hip/hip_bf16.h>
#include <math.h>

#define NEG_SLOPE 0.2f
#define SCAN_B 1024   // elements per scan block (256 threads x 4)

__device__ __forceinline__ float leaky(float v) { return v >= 0.0f ? v : NEG_SLOPE * v; }
__device__ __forceinline__ int clampi(int v, int lo, int hi) {
    return v < lo ? lo : (v > hi ? hi : v);
}

// K0: zero-init offsets + partials (replaces hipMemsetAsync; graph-capture safe).
__global__ __launch_bounds__(256) void k_zero(int* __restrict__ p, int n)
{
    int i = blockIdx.x * 256 + threadIdx.x;
    if (i < n) p[i] = 0;
}

// K1: h = x @ W (IN=128, OUT=64) stored bf16; fused fp32 a_s = h@att_src,
// a_d = h@att_dst. 256 threads (4 waves), 32 nodes/block. W + 32 x-rows in LDS.
__global__ __launch_bounds__(256) void k_linear(
    const float* __restrict__ x, const float* __restrict__ W,
    const float* __restrict__ att_src, const float* __restrict__ att_dst,
    __hip_bfloat16* __restrict__ h, float* __restrict__ a_s,
    float* __restrict__ a_d, int N)
{
    __shared__ float sW[128 * 64];
    __shared__ float sx[32 * 128];
    const int tid  = threadIdx.x;
    const int base = blockIdx.x * 32;

    const float4* W4  = (const float4*)W;
    float4*       sW4 = (float4*)sW;
#pragma unroll
    for (int i = 0; i < 8; ++i) sW4[tid + i * 256] = W4[tid + i * 256];

    const int nvalid = (N - base) < 32 ? (N - base) : 32;
    const int lim4   = nvalid * 32;
    const float4* x4  = (const float4*)x + (size_t)base * 32;
    float4*       sx4 = (float4*)sx;
#pragma unroll
    for (int i = 0; i < 4; ++i) {
        int idx = tid + i * 256;
        if (idx < lim4) sx4[idx] = x4[idx];
    }
    __syncthreads();

    const int o = tid & 63;   // output feature
    const int w = tid >> 6;   // wave id

    float acc[8];
#pragma unroll
    for (int j = 0; j < 8; ++j) acc[j] = 0.0f;

    const float* sxw = sx + (w * 8) * 128;
    for (int k = 0; k < 128; ++k) {
        float wk = sW[k * 64 + o];
#pragma unroll
        for (int j = 0; j < 8; ++j) acc[j] += sxw[j * 128 + k] * wk;
    }

    const float vs = att_src[o];
    const float vd = att_dst[o];
#pragma unroll
    for (int j = 0; j < 8; ++j) {
        int n = base + w * 8 + j;   // wave-uniform
        if (n < N) {
            h[(size_t)n * 64 + o] = __float2bfloat16(acc[j]);
            float s = acc[j] * vs;
            float d = acc[j] * vd;
#pragma unroll
            for (int m = 32; m > 0; m >>= 1) {
                s += __shfl_xor(s, m, 64);
                d += __shfl_xor(d, m, 64);
            }
            if (o == 0) { a_s[n] = s; a_d[n] = d; }
        }
    }
}

// K2: histogram of destination degrees into off[] (pre-zeroed).
__global__ __launch_bounds__(256) void k_hist(
    const int* __restrict__ ei, int* __restrict__ off, int E, int N)
{
    int t = blockIdx.x * 256 + threadIdx.x;
    if (t >= E) return;
    int dst = clampi(ei[E + t], 0, N - 1);
    atomicAdd(off + dst, 1);
}

// K3a: per-block exclusive scan IN PLACE (1024 elems/block), totals to partial[].
__global__ __launch_bounds__(256) void k_scan_a(
    int* __restrict__ arr, int* __restrict__ partial, int N)
{
    __shared__ int s[256];
    int t = threadIdx.x;
    int base = blockIdx.x * SCAN_B + t * 4;
    int v0 = (base + 0 < N) ? arr[base + 0] : 0;
    int v1 = (base + 1 < N) ? arr[base + 1] : 0;
    int v2 = (base + 2 < N) ? arr[base + 2] : 0;
    int v3 = (base + 3 < N) ? arr[base + 3] : 0;
    int tsum = v0 + v1 + v2 + v3;
    s[t] = tsum;
    __syncthreads();
    for (int d = 1; d < 256; d <<= 1) {
        int xv = (t >= d) ? s[t - d] : 0;
        __syncthreads();
        s[t] += xv;
        __syncthreads();
    }
    int excl = s[t] - tsum;
    if (t == 255) partial[blockIdx.x] = s[255];
    if (base + 0 < N) arr[base + 0] = excl;
    if (base + 1 < N) arr[base + 1] = excl + v0;
    if (base + 2 < N) arr[base + 2] = excl + v0 + v1;
    if (base + 3 < N) arr[base + 3] = excl + v0 + v1 + v2;
}

// K3b: single-block (256 threads) exclusive scan of up to 1024 partials, in place.
__global__ __launch_bounds__(256) void k_scan_b(int* __restrict__ partial, int NB)
{
    __shared__ int s[256];
    int t = threadIdx.x;
    int base = t * 4;
    int v0 = (base + 0 < NB) ? partial[base + 0] : 0;
    int v1 = (base + 1 < NB) ? partial[base + 1] : 0;
    int v2 = (base + 2 < NB) ? partial[base + 2] : 0;
    int v3 = (base + 3 < NB) ? partial[base + 3] : 0;
    int tsum = v0 + v1 + v2 + v3;
    s[t] = tsum;
    __syncthreads();
    for (int d = 1; d < 256; d <<= 1) {
        int xv = (t >= d) ? s[t - d] : 0;
        __syncthreads();
        s[t] += xv;
        __syncthreads();
    }
    int excl = s[t] - tsum;
    if (base + 0 < NB) partial[base + 0] = excl;
    if (base + 1 < NB) partial[base + 1] = excl + v0;
    if (base + 2 < NB) partial[base + 2] = excl + v0 + v1;
    if (base + 3 < NB) partial[base + 3] = excl + v0 + v1 + v2;
}

// K3c: add scanned block offsets.
__global__ __launch_bounds__(256) void k_scan_c(
    int* __restrict__ off, const int* __restrict__ partial, int N)
{
    int i = blockIdx.x * 256 + threadIdx.x;
    if (i >= N) return;
    off[i] += partial[i / SCAN_B];
}

// K4: counting-sort scatter. Bumps off[dst]; afterwards off[n] = END of n's list.
__global__ __launch_bounds__(256) void k_scatter(
    const int* __restrict__ ei, int* __restrict__ off,
    int* __restrict__ sorted_src, int E, int N)
{
    int t = blockIdx.x * 256 + threadIdx.x;
    if (t >= E) return;
    int src = clampi(ei[t],     0, N - 1);
    int dst = clampi(ei[E + t], 0, N - 1);
    int pos = atomicAdd(off + dst, 1);
    pos = clampi(pos, 0, E - 1);          // fault-proof: never write past sorted_src
    sorted_src[pos] = src;
}

// K5: one wave per dst node. Online softmax over its edge list (chunks of 64),
// self-loop included, register accumulator, single coalesced write. No atomics.
__global__ __launch_bounds__(256) void k_agg(
    const int* __restrict__ sorted_src, const int* __restrict__ off,
    const float* __restrict__ a_s, const float* __restrict__ a_d,
    const __hip_bfloat16* __restrict__ h, const float* __restrict__ bias,
    float* __restrict__ out, int N, int E)
{
    int lane = threadIdx.x & 63;
    int n = blockIdx.x * 4 + (threadIdx.x >> 6);   // wave-uniform
    if (n >= N) return;

    int start = (n > 0) ? off[n - 1] : 0;
    int end   = off[n];
    start = clampi(start, 0, E);
    end   = clampi(end, start, E);        // fault-proof + loop-bound-proof
    float adn = a_d[n];

    // self loop: weight 1 at logit m
    float m   = leaky(a_s[n] + adn);
    float l   = 1.0f;
    float acc = __bfloat162float(h[(size_t)n * 64 + lane]);

    for (int c0 = start; c0 < end; c0 += 64) {
        int nc = min(64, end - c0);
        int   srcl = (lane < nc) ? clampi(sorted_src[c0 + lane], 0, N - 1) : 0;
        float el   = (lane < nc) ? leaky(a_s[srcl] + adn) : -INFINITY;

        // chunk max
        float cm = el;
#pragma unroll
        for (int s = 32; s > 0; s >>= 1) cm = fmaxf(cm, __shfl_xor(cm, s, 64));
        float mnew  = fmaxf(m, cm);
        float scale = __expf(m - mnew);
        float wl    = (lane < nc) ? __expf(el - mnew) : 0.0f;

        // chunk weight sum
        float wsum = wl;
#pragma unroll
        for (int s = 32; s > 0; s >>= 1) wsum += __shfl_xor(wsum, s, 64);

        acc *= scale;
        l = l * scale + wsum;
        m = mnew;

        // gather h rows, software-pipelined by one
        int   sj = __shfl(srcl, 0, 64);
        float hv = __bfloat162float(h[(size_t)sj * 64 + lane]);
        for (int j = 0; j < nc; ++j) {
            float wj = __shfl(wl, j, 64);
            float hnext = 0.0f;
            if (j + 1 < nc) {
                int sn = __shfl(srcl, j + 1, 64);
                hnext = __bfloat162float(h[(size_t)sn * 64 + lane]);
            }
            acc = fmaf(wj, hv, acc);
            hv = hnext;
        }
    }
    out[(size_t)n * 64 + lane] = bias[lane] + acc / l;
}

extern "C" void kernel_launch(void* const* d_in, const int* in_sizes, int n_in,
                              void* d_out, int out_size, void* d_ws, size_t ws_size,
                              hipStream_t stream)
{
    const float* x       = (const float*)d_in[0];
    const int*   ei      = (const int*)d_in[1];      // int32 per harness contract
    const float* W       = (const float*)d_in[2];
    const float* att_src = (const float*)d_in[3];
    const float* att_dst = (const float*)d_in[4];
    const float* bias    = (const float*)d_in[5];
    float*       out     = (float*)d_out;

    const int N = in_sizes[0] / 128;   // 100000
    const int E = in_sizes[1] / 2;     // 1600000

    // ws layout (~20.4 MB): h_bf16[N*64] | a_s[N] | a_d[N] | off[N] | partial[1024] | sorted_src[E]
    __hip_bfloat16* h          = (__hip_bfloat16*)d_ws;
    float*          a_s        = (float*)(h + (size_t)N * 64);
    float*          a_d        = a_s + N;
    int*            off        = (int*)(a_d + N);
    int*            partial    = off + N;
    int*            sorted_src = partial + 1024;

    int nb_lin  = (N + 31) / 32;
    int nb_zero = (N + 1024 + 255) / 256;      // off + partial
    int nb_node = (N + 255) / 256;
    int nb_edge = (E + 255) / 256;
    int nb_scan = (N + SCAN_B - 1) / SCAN_B;   // 98 blocks (<=1024)
    int nb_agg  = (N + 3) / 4;

    k_zero   <<<nb_zero, 256, 0, stream>>>(off, N + 1024);
    k_hist   <<<nb_edge, 256, 0, stream>>>(ei, off, E, N);
    k_linear <<<nb_lin,  256, 0, stream>>>(x, W, att_src, att_dst, h, a_s, a_d, N);
    k_scan_a <<<nb_scan, 256, 0, stream>>>(off, partial, N);
    k_scan_b <<<1,       256, 0, stream>>>(partial, nb_scan);
    k_scan_c <<<nb_node, 256, 0, stream>>>(off, partial, N);
    k_scatter<<<nb_edge, 256, 0, stream>>>(ei, off, sorted_src, E, N);
    k_agg    <<<nb_agg,  256, 0, stream>>>(sorted_src, off, a_s, a_d, h, bias, out, N, E);
}